// Round 1
// baseline (713.808 us; speedup 1.0000x reference)
//
#include <hip/hip_runtime.h>
#include <math.h>

#define HH 128
#define WW 128
#define NIMG 4
#define PP 11
#define KSIM 16
#define STRIDE_S 3
#define VRAD 32
#define WINW 65             // 2V+1
#define NCAND (WINW*WINW)   // 4225
#define HREF 40
#define WREF 40
#define NPOS 118            // H-P+1
#define NPATCH 121          // P*P
#define WROWS 75            // 2V+P
#define WPITCH 84           // padded (>=75+17 headroom for 18-wide reg reads), 16B-aligned rows
#define NGROUP (NIMG*HREF*WREF) // 6400
#define EPS_E 30.25f        // n*alpha^2*sigma^2 = 121*0.25
#define DE_C 151.25f        // D+E = 121 + 30.25
#define INFD 3.0e38f

// ---------------------------------------------------------------------------
// Stage 1: block matching. One block per reference patch.
// Candidate window (75x75) staged in LDS; each thread computes an 8-wide
// dc-strip of candidates with the 18-float window segment register-cached.
// Top-16 selection: cached per-thread local min + shfl reduce, owner rescan.
// ---------------------------------------------------------------------------
__global__ __launch_bounds__(256)
void bm_kernel(const float* __restrict__ y, int* __restrict__ inds)
{
    __shared__ float win[WROWS][WPITCH];
    __shared__ float dist[NCAND];
    __shared__ float swv[4];
    __shared__ int   swi[4];

    const int blk = blockIdx.x;
    const int n   = blk / (HREF*WREF);
    const int rem = blk % (HREF*WREF);
    const int i   = rem / WREF;
    const int j   = rem % WREF;
    const int hr  = i * STRIDE_S;
    const int wr  = j * STRIDE_S;
    const float* img = y + n * HH * WW;
    const int tid = threadIdx.x;

    // load candidate window (zero outside image; those candidates get masked)
    for (int t = tid; t < WROWS * WPITCH; t += 256) {
        int r = t / WPITCH, c = t % WPITCH;
        int gr = hr - VRAD + r, gc = wr - VRAD + c;
        float v = 0.f;
        if (c < WROWS && gr >= 0 && gr < HH && gc >= 0 && gc < WW)
            v = img[gr * WW + gc];
        win[r][c] = v;
    }
    __syncthreads();

    // distances: task = (drx, dc-group of 8); 65 * 9 = 585 tasks
    for (int task = tid; task < WINW * 9; task += 256) {
        int drx = task / 9;
        int g   = task % 9;
        int c0  = g * 8;
        int rr  = hr + drx - VRAD;
        bool rowok = (rr >= 0 && rr <= HH - PP);
        float acc[8];
#pragma unroll
        for (int c = 0; c < 8; c++) acc[c] = 0.f;
        if (rowok) {
            for (int a = 0; a < PP; a++) {
                const float* wrow = &win[drx + a][c0];
                const float* rrow = &win[VRAD + a][VRAD];
                float wv[18];
#pragma unroll
                for (int t2 = 0; t2 < 18; t2++) wv[t2] = wrow[t2];
#pragma unroll
                for (int b = 0; b < PP; b++) {
                    float rv = rrow[b];   // wave-uniform LDS broadcast
#pragma unroll
                    for (int c = 0; c < 8; c++) {
                        float d = wv[b + c] - rv;
                        acc[c] += d * d;
                    }
                }
            }
        }
#pragma unroll
        for (int c = 0; c < 8; c++) {
            int dcx = c0 + c;
            if (dcx < WINW) {
                int cc = wr + dcx - VRAD;
                float val = (rowok && cc >= 0 && cc <= WW - PP) ? acc[c] : INFD;
                dist[drx * WINW + dcx] = val;
            }
        }
    }
    __syncthreads();
    if (tid == 0) dist[VRAD * WINW + VRAD] = -INFD;   // reference always kept
    __syncthreads();

    // cached per-thread local min over own strided strip
    float lval = INFD; int lidx = -1;
    for (int t = tid; t < NCAND; t += 256) {
        float v = dist[t];
        if (v < lval) { lval = v; lidx = t; }
    }

    for (int sel = 0; sel < KSIM; sel++) {
        float rv = lval; int ri = lidx;
#pragma unroll
        for (int off = 32; off > 0; off >>= 1) {
            float ov = __shfl_down(rv, off);
            int   oi = __shfl_down(ri, off);
            if (ov < rv) { rv = ov; ri = oi; }
        }
        if ((tid & 63) == 0) { swv[tid >> 6] = rv; swi[tid >> 6] = ri; }
        __syncthreads();
        float bval = swv[0]; int bidx = swi[0];
#pragma unroll
        for (int w2 = 1; w2 < 4; w2++)
            if (swv[w2] < bval) { bval = swv[w2]; bidx = swi[w2]; }
        if (tid == 0) {
            int drx = bidx / WINW, dcx = bidx % WINW;
            int prr = hr + drx - VRAD, pcc = wr + dcx - VRAD;
            inds[blk * KSIM + sel] = prr * NPOS + pcc;
        }
        __syncthreads();  // swv/swi consumed before next round overwrites
        if (bidx == lidx) {           // unique owner (strips are tid mod 256)
            dist[bidx] = INFD;
            lval = INFD; lidx = -1;
            for (int t = tid; t < NCAND; t += 256) {
                float v = dist[t];
                if (v < lval) { lval = v; lidx = t; }
            }
        }
    }
}

// ---------------------------------------------------------------------------
// Stage 2+3: per-group denoise (Q=YY^T+E*I, Cholesky inverse, theta, X_hat,
// weights) and direct weighted-patch scatter onto num/den images.
// ---------------------------------------------------------------------------
__global__ __launch_bounds__(256)
void dn_kernel(const float* __restrict__ y, const int* __restrict__ inds,
               float* __restrict__ num, float* __restrict__ den)
{
    __shared__ float Ys[KSIM][NPATCH];
    __shared__ float Qs[KSIM][KSIM];
    __shared__ float Qinvs[KSIM][KSIM];
    __shared__ float thetas[KSIM][KSIM];
    __shared__ float s1[KSIM];
    __shared__ float ws16[KSIM];
    __shared__ float s2s;
    __shared__ int prow[KSIM], pcol[KSIM];

    const int g = blockIdx.x;
    const int n = g / (HREF*WREF);
    const float* img = y + n * HH * WW;
    float* numI = num + n * HH * WW;
    float* denI = den + n * HH * WW;
    const int tid = threadIdx.x;

    if (tid < KSIM) {
        int idx = inds[g * KSIM + tid];
        prow[tid] = idx / NPOS;
        pcol[tid] = idx % NPOS;
    }
    __syncthreads();

    for (int t = tid; t < KSIM * NPATCH; t += 256) {
        int k = t / NPATCH, jj = t % NPATCH;
        int a = jj / PP, b = jj % PP;
        Ys[k][jj] = img[(prow[k] + a) * WW + pcol[k] + b];
    }
    __syncthreads();

    {   // Q = Y Y^T + E I   (256 threads = full 16x16)
        int a = tid >> 4, b = tid & 15;
        float s = 0.f;
        for (int jj = 0; jj < NPATCH; jj++)
            s += Ys[a][jj] * Ys[b][jj];
        if (a == b) s += EPS_E;
        Qs[a][b] = s;
    }
    __syncthreads();

    // in-place lower Cholesky (right-looking), barriers at block level
    for (int c = 0; c < KSIM; c++) {
        if (tid == 0) Qs[c][c] = sqrtf(Qs[c][c]);
        __syncthreads();
        if (tid > c && tid < KSIM) Qs[tid][c] /= Qs[c][c];
        __syncthreads();
        {
            int a = tid >> 4, b = tid & 15;
            if (a > c && b > c && b <= a) Qs[a][b] -= Qs[a][c] * Qs[b][c];
        }
        __syncthreads();
    }

    // per-column forward+back substitution -> Qinv (fully unrolled: static idx)
    if (tid < KSIM) {
        float z[KSIM];
#pragma unroll
        for (int r = 0; r < KSIM; r++) {
            float s = (r == tid) ? 1.f : 0.f;
#pragma unroll
            for (int m = 0; m < KSIM; m++)
                if (m < r) s -= Qs[r][m] * z[m];
            z[r] = s / Qs[r][r];
        }
#pragma unroll
        for (int r = KSIM - 1; r >= 0; r--) {
            float s = z[r];
#pragma unroll
            for (int m = 0; m < KSIM; m++)
                if (m > r) s -= Qs[m][r] * z[m];
            z[r] = s / Qs[r][r];
        }
#pragma unroll
        for (int r = 0; r < KSIM; r++) Qinvs[r][tid] = z[r];
    }
    __syncthreads();

    if (tid < KSIM) {
        float s = 0.f;
#pragma unroll
        for (int b = 0; b < KSIM; b++) s += Qinvs[tid][b];
        s1[tid] = s;
    }
    __syncthreads();
    if (tid == 0) {
        float s = 0.f;
#pragma unroll
        for (int a = 0; a < KSIM; a++) s += s1[a];
        s2s = s;
    }
    __syncthreads();

    {   // theta (symmetric; reference's transpose is a mathematical no-op)
        int a = tid >> 4, b = tid & 15;
        float th = ((a == b) ? 1.f : 0.f)
                 - (Qinvs[a][b] - s1[a] * s1[b] / s2s) * DE_C;
        thetas[a][b] = th;
    }
    __syncthreads();

    if (tid < KSIM) {   // weights[r] = 1/clip(sum_m theta[m][r]^2, 1/k, 1)
        float s = 0.f;
#pragma unroll
        for (int m = 0; m < KSIM; m++) s += thetas[m][tid] * thetas[m][tid];
        s = fminf(fmaxf(s, 1.f / (float)KSIM), 1.f);
        ws16[tid] = 1.f / s;
    }
    __syncthreads();

    // X_hat = theta^T Y, then scatter weighted patch + weight onto num/den
    for (int t = tid; t < KSIM * NPATCH; t += 256) {
        int r = t / NPATCH, jj = t % NPATCH;
        float xh = 0.f;
#pragma unroll
        for (int m = 0; m < KSIM; m++) xh += thetas[m][r] * Ys[m][jj];
        float wv = ws16[r];
        int a = jj / PP, b = jj % PP;
        int px = (prow[r] + a) * WW + pcol[r] + b;
        atomicAdd(&numI[px], wv * xh);
        atomicAdd(&denI[px], wv);
    }
}

// ---------------------------------------------------------------------------
// Stage 4: out = num / den  (den > 0 everywhere: reference patches cover grid)
// ---------------------------------------------------------------------------
__global__ __launch_bounds__(256)
void fin_kernel(const float* __restrict__ num, const float* __restrict__ den,
                float* __restrict__ out)
{
    int t = blockIdx.x * 256 + threadIdx.x;
    if (t < NIMG * HH * WW) out[t] = num[t] / den[t];
}

extern "C" void kernel_launch(void* const* d_in, const int* in_sizes, int n_in,
                              void* d_out, int out_size, void* d_ws, size_t ws_size,
                              hipStream_t stream)
{
    const float* y = (const float*)d_in[0];
    float* out = (float*)d_out;

    // workspace layout: num (65536 f32) | den (65536 f32) | inds (102400 i32)
    float* num = (float*)d_ws;
    float* den = num + NIMG * HH * WW;
    int*   inds = (int*)(den + NIMG * HH * WW);

    hipMemsetAsync(num, 0, (size_t)2 * NIMG * HH * WW * sizeof(float), stream);
    bm_kernel<<<NGROUP, 256, 0, stream>>>(y, inds);
    dn_kernel<<<NGROUP, 256, 0, stream>>>(y, inds, num, den);
    fin_kernel<<<(NIMG * HH * WW + 255) / 256, 256, 0, stream>>>(num, den, out);
}

// Round 2
// 524.231 us; speedup vs baseline: 1.3616x; 1.3616x over previous
//
#include <hip/hip_runtime.h>
#include <math.h>

#define HH 128
#define WW 128
#define NIMG 4
#define PP 11
#define KSIM 16
#define STRIDE_S 3
#define VRAD 32
#define WINW 65             // 2V+1
#define NTASK (WINW*9)      // 585 tasks: (drx, 8-wide dc strip)
#define HREF 40
#define WREF 40
#define NPOS 118            // H-P+1
#define WROWS 75            // 2V+P
#define WPITCH 84           // 16B-aligned rows; headroom for 18-wide reads (max col 81)
#define NGROUP (NIMG*HREF*WREF) // 6400
#define EPS_E 30.25f        // n*alpha^2*sigma^2 = 121*0.25
#define DE_C 151.25f        // D+E = 121 + 30.25
#define INFD 3.0e38f
#define RTASK (VRAD*9 + VRAD/8)   // 292: task holding the reference candidate (c=0)

// ---------------------------------------------------------------------------
// Stage 1: block matching. One block per reference patch.
// dist = |c|^2 - 2<c,r>  (same ordering as SSD; reference's own formulation).
// Window in LDS; per-thread distances in STATIC registers (no dist LDS).
// colsq accumulated in registers from the already-loaded wv values.
// ---------------------------------------------------------------------------
__global__ __launch_bounds__(256, 4)
void bm_kernel(const float* __restrict__ y, int* __restrict__ inds)
{
    __shared__ float win[WROWS][WPITCH];   // 25.2 KB
    __shared__ float swv[4];
    __shared__ int   swi[4];

    const int blk = blockIdx.x;
    const int n   = blk / (HREF*WREF);
    const int rem = blk % (HREF*WREF);
    const int hr  = (rem / WREF) * STRIDE_S;
    const int wr  = (rem % WREF) * STRIDE_S;
    const float* img = y + n * HH * WW;
    const int tid = threadIdx.x;

    // load candidate window (zero outside image; those candidates get masked)
    for (int t = tid; t < WROWS * WPITCH; t += 256) {
        int r = t / WPITCH, c = t % WPITCH;
        int gr = hr - VRAD + r, gc = wr - VRAD + c;
        float v = 0.f;
        if (c < WROWS && gr >= 0 && gr < HH && gc >= 0 && gc < WW)
            v = img[gr * WW + gc];
        win[r][c] = v;
    }
    __syncthreads();

    // per-thread distances: 3 slots x 8 candidates, static register indexing
    float d[3][8];
#pragma unroll
    for (int s = 0; s < 3; s++)
#pragma unroll
        for (int c = 0; c < 8; c++) d[s][c] = INFD;

#pragma unroll
    for (int s = 0; s < 3; s++) {
        int task = tid + (s << 8);
        if (task < NTASK) {
            int drx = task / 9;
            int c0  = (task % 9) * 8;
            int rr  = hr + drx - VRAD;
            bool rowok = (rr >= 0 && rr <= HH - PP);
            if (rowok) {
                float dot[8];
                float colsq[18];
#pragma unroll
                for (int c = 0; c < 8; c++) dot[c] = 0.f;
#pragma unroll
                for (int j2 = 0; j2 < 18; j2++) colsq[j2] = 0.f;
                for (int a = 0; a < PP; a++) {
                    const float* wrow = &win[drx + a][c0];
                    const float* rrow = &win[VRAD + a][VRAD];
                    float wv[18];
#pragma unroll
                    for (int j2 = 0; j2 < 18; j2++) wv[j2] = wrow[j2];
#pragma unroll
                    for (int j2 = 0; j2 < 18; j2++) colsq[j2] += wv[j2] * wv[j2];
#pragma unroll
                    for (int b = 0; b < PP; b++) {
                        float rv = rrow[b];   // wave-uniform LDS broadcast
#pragma unroll
                        for (int c = 0; c < 8; c++)
                            dot[c] += wv[b + c] * rv;
                    }
                }
                // inclusive prefix over colsq (in place)
#pragma unroll
                for (int j2 = 1; j2 < 18; j2++) colsq[j2] += colsq[j2 - 1];
#pragma unroll
                for (int c = 0; c < 8; c++) {
                    int dcx = c0 + c;
                    int cc  = wr + dcx - VRAD;
                    float norm = colsq[c + 10] - (c ? colsq[c - 1] : 0.f);
                    if (dcx < WINW && cc >= 0 && cc <= WW - PP)
                        d[s][c] = norm - 2.f * dot[c];
                }
            }
            if (task == RTASK) d[s][0] = -INFD;   // reference always kept first
        }
    }

    // cached per-thread argmin (local code = s*8+c)
    float lval = INFD; int lidx = 0;
#pragma unroll
    for (int s = 0; s < 3; s++)
#pragma unroll
        for (int c = 0; c < 8; c++)
            if (d[s][c] < lval) { lval = d[s][c]; lidx = (s << 3) | c; }

    for (int sel = 0; sel < KSIM; sel++) {
        // global candidate id: gid = task*8 + c
        float rv = lval;
        int   ri = ((tid + ((lidx >> 3) << 8)) << 3) | (lidx & 7);
#pragma unroll
        for (int off = 32; off > 0; off >>= 1) {
            float ov = __shfl_down(rv, off);
            int   oi = __shfl_down(ri, off);
            if (ov < rv) { rv = ov; ri = oi; }
        }
        if ((tid & 63) == 0) { swv[tid >> 6] = rv; swi[tid >> 6] = ri; }
        __syncthreads();
        float bval = swv[0]; int bidx = swi[0];
#pragma unroll
        for (int w2 = 1; w2 < 4; w2++)
            if (swv[w2] < bval) { bval = swv[w2]; bidx = swi[w2]; }
        if (tid == 0) {
            int task = bidx >> 3;
            int drx = task / 9, dcx = (task % 9) * 8 + (bidx & 7);
            int prr = hr + drx - VRAD, pcc = wr + dcx - VRAD;
            inds[blk * KSIM + sel] = prr * NPOS + pcc;
        }
        __syncthreads();  // swv/swi consumed before next round overwrites
        int otid = (bidx >> 3) & 255;
        if (tid == otid) {                 // owner: remove + rescan registers
            int code = (((bidx >> 3) >> 8) << 3) | (bidx & 7);
            lval = INFD; lidx = 0;
#pragma unroll
            for (int s = 0; s < 3; s++)
#pragma unroll
                for (int c = 0; c < 8; c++) {
                    if (((s << 3) | c) == code) d[s][c] = INFD;
                    if (d[s][c] < lval) { lval = d[s][c]; lidx = (s << 3) | c; }
                }
        }
    }
}

// ---------------------------------------------------------------------------
// Stage 2+3: per-group denoise + weighted scatter onto replicated (num,den)
// float2 images. Block->group shuffle decorrelates concurrent atomics.
// ---------------------------------------------------------------------------
__global__ __launch_bounds__(256)
void dn_kernel(const float* __restrict__ y, const int* __restrict__ inds,
               float2* __restrict__ nd, int R)
{
    __shared__ float Ys[KSIM][122];       // pitch 122 (121+1)
    __shared__ float Qs[KSIM][KSIM];
    __shared__ float Qinvs[KSIM][KSIM];
    __shared__ float thetas[KSIM][KSIM];
    __shared__ float s1[KSIM];
    __shared__ float ws16[KSIM];
    __shared__ float s2s;
    __shared__ int prow[KSIM], pcol[KSIM];

    const int g = (int)(((long long)blockIdx.x * 2753) % NGROUP);  // bijective
    const int n = g / (HREF*WREF);
    const float* img = y + n * HH * WW;
    float2* ndI = nd + ((size_t)(blockIdx.x & (R - 1)) * NIMG + n) * HH * WW;
    const int tid = threadIdx.x;

    if (tid < KSIM) {
        int idx = inds[g * KSIM + tid];
        prow[tid] = idx / NPOS;
        pcol[tid] = idx % NPOS;
    }
    __syncthreads();

    for (int t = tid; t < KSIM * 121; t += 256) {
        int k = t / 121, jj = t % 121;
        int a = jj / PP, b = jj % PP;
        Ys[k][jj] = img[(prow[k] + a) * WW + pcol[k] + b];
    }
    __syncthreads();

    {   // Q = Y Y^T + E I   (256 threads = full 16x16)
        int a = tid >> 4, b = tid & 15;
        float s = 0.f;
        for (int jj = 0; jj < 121; jj++)
            s += Ys[a][jj] * Ys[b][jj];
        if (a == b) s += EPS_E;
        Qs[a][b] = s;
    }
    __syncthreads();

    // in-place lower Cholesky (right-looking)
    for (int c = 0; c < KSIM; c++) {
        if (tid == 0) Qs[c][c] = sqrtf(Qs[c][c]);
        __syncthreads();
        if (tid > c && tid < KSIM) Qs[tid][c] /= Qs[c][c];
        __syncthreads();
        {
            int a = tid >> 4, b = tid & 15;
            if (a > c && b > c && b <= a) Qs[a][b] -= Qs[a][c] * Qs[b][c];
        }
        __syncthreads();
    }

    // per-column forward+back substitution -> Qinv (static register indexing)
    if (tid < KSIM) {
        float z[KSIM];
#pragma unroll
        for (int r = 0; r < KSIM; r++) {
            float s = (r == tid) ? 1.f : 0.f;
#pragma unroll
            for (int m = 0; m < KSIM; m++)
                if (m < r) s -= Qs[r][m] * z[m];
            z[r] = s / Qs[r][r];
        }
#pragma unroll
        for (int r = KSIM - 1; r >= 0; r--) {
            float s = z[r];
#pragma unroll
            for (int m = 0; m < KSIM; m++)
                if (m > r) s -= Qs[m][r] * z[m];
            z[r] = s / Qs[r][r];
        }
#pragma unroll
        for (int r = 0; r < KSIM; r++) Qinvs[r][tid] = z[r];
    }
    __syncthreads();

    if (tid < KSIM) {
        float s = 0.f;
#pragma unroll
        for (int b = 0; b < KSIM; b++) s += Qinvs[tid][b];
        s1[tid] = s;
    }
    __syncthreads();
    if (tid == 0) {
        float s = 0.f;
#pragma unroll
        for (int a = 0; a < KSIM; a++) s += s1[a];
        s2s = s;
    }
    __syncthreads();

    {   // theta (symmetric: reference's transpose is a no-op)
        int a = tid >> 4, b = tid & 15;
        float th = ((a == b) ? 1.f : 0.f)
                 - (Qinvs[a][b] - s1[a] * s1[b] / s2s) * DE_C;
        thetas[a][b] = th;
    }
    __syncthreads();

    if (tid < KSIM) {   // weights[r] = 1/clip(sum_m theta[m][r]^2, 1/k, 1)
        float s = 0.f;
#pragma unroll
        for (int m = 0; m < KSIM; m++) s += thetas[m][tid] * thetas[m][tid];
        s = fminf(fmaxf(s, 1.f / (float)KSIM), 1.f);
        ws16[tid] = 1.f / s;
    }
    __syncthreads();

    // X_hat = theta^T Y; scatter weighted patch + weight onto (num,den) pairs
    for (int t = tid; t < KSIM * 121; t += 256) {
        int r = t / 121, jj = t % 121;
        float xh = 0.f;
#pragma unroll
        for (int m = 0; m < KSIM; m++) xh += thetas[m][r] * Ys[m][jj];
        float wv = ws16[r];
        int a = jj / PP, b = jj % PP;
        int px = (prow[r] + a) * WW + pcol[r] + b;
#if defined(__has_builtin) && __has_builtin(__builtin_amdgcn_global_atomic_fadd_v2f32)
        typedef float v2f __attribute__((ext_vector_type(2)));
        __builtin_amdgcn_global_atomic_fadd_v2f32((v2f*)&ndI[px], (v2f){wv * xh, wv});
#else
        atomicAdd(&ndI[px].x, wv * xh);
        atomicAdd(&ndI[px].y, wv);
#endif
    }
}

// ---------------------------------------------------------------------------
// Stage 4: out = sum_r num_r / sum_r den_r
// ---------------------------------------------------------------------------
__global__ __launch_bounds__(256)
void fin_kernel(const float2* __restrict__ nd, float* __restrict__ out, int R)
{
    int t = blockIdx.x * 256 + threadIdx.x;
    if (t < NIMG * HH * WW) {
        float sn = 0.f, sd = 0.f;
        for (int r = 0; r < R; r++) {
            float2 v = nd[(size_t)r * NIMG * HH * WW + t];
            sn += v.x; sd += v.y;
        }
        out[t] = sn / sd;
    }
}

extern "C" void kernel_launch(void* const* d_in, const int* in_sizes, int n_in,
                              void* d_out, int out_size, void* d_ws, size_t ws_size,
                              hipStream_t stream)
{
    const float* y = (const float*)d_in[0];
    float* out = (float*)d_out;

    // workspace: nd replicas (float2 per pixel per image) | inds
    size_t indsBytes = (size_t)NGROUP * KSIM * sizeof(int);
    size_t perRep    = (size_t)NIMG * HH * WW * sizeof(float2);
    int R = 1;
    while (R < 4 && indsBytes + perRep * (size_t)(R * 2) <= ws_size) R <<= 1;

    float2* nd  = (float2*)d_ws;
    int*    inds = (int*)((char*)d_ws + perRep * (size_t)R);

    hipMemsetAsync(nd, 0, perRep * (size_t)R, stream);
    bm_kernel<<<NGROUP, 256, 0, stream>>>(y, inds);
    dn_kernel<<<NGROUP, 256, 0, stream>>>(y, inds, nd, R);
    fin_kernel<<<(NIMG * HH * WW + 255) / 256, 256, 0, stream>>>(nd, out, R);
}

// Round 3
// 476.612 us; speedup vs baseline: 1.4977x; 1.0999x over previous
//
#include <hip/hip_runtime.h>
#include <math.h>

#define HH 128
#define WW 128
#define NIMG 4
#define PP 11
#define KSIM 16
#define STRIDE_S 3
#define VRAD 32
#define WINW 65             // 2V+1
#define NTASK (WINW*9)      // 585 tasks: (drx, 8-wide dc strip)
#define HREF 40
#define WREF 40
#define NPOS 118            // H-P+1
#define WROWS 75            // 2V+P
#define WPITCH 84           // 16B-aligned rows; headroom for 18-wide reads
#define NGROUP (NIMG*HREF*WREF) // 6400
#define EPS_E 30.25f        // n*alpha^2*sigma^2 = 121*0.25
#define DE_C 151.25f        // D+E = 121 + 30.25
#define INFD 3.0e38f
#define RTASK (VRAD*9 + VRAD/8)   // 292: task holding the reference candidate (c=0)

#define TDIM 4              // 4x4 groups per dn tile
#define NTIL (HREF/TDIM)    // 10
#define FOOT 84             // pixel footprint of a tile: 3*3+65+10 = 84
#define FPITCH 85

// ---------------------------------------------------------------------------
// Stage 1: block matching (unchanged from R1). One block per reference patch.
// ---------------------------------------------------------------------------
__global__ __launch_bounds__(256, 4)
void bm_kernel(const float* __restrict__ y, int* __restrict__ inds)
{
    __shared__ float win[WROWS][WPITCH];   // 25.2 KB
    __shared__ float swv[4];
    __shared__ int   swi[4];

    const int blk = blockIdx.x;
    const int n   = blk / (HREF*WREF);
    const int rem = blk % (HREF*WREF);
    const int hr  = (rem / WREF) * STRIDE_S;
    const int wr  = (rem % WREF) * STRIDE_S;
    const float* img = y + n * HH * WW;
    const int tid = threadIdx.x;

    for (int t = tid; t < WROWS * WPITCH; t += 256) {
        int r = t / WPITCH, c = t % WPITCH;
        int gr = hr - VRAD + r, gc = wr - VRAD + c;
        float v = 0.f;
        if (c < WROWS && gr >= 0 && gr < HH && gc >= 0 && gc < WW)
            v = img[gr * WW + gc];
        win[r][c] = v;
    }
    __syncthreads();

    float d[3][8];
#pragma unroll
    for (int s = 0; s < 3; s++)
#pragma unroll
        for (int c = 0; c < 8; c++) d[s][c] = INFD;

#pragma unroll
    for (int s = 0; s < 3; s++) {
        int task = tid + (s << 8);
        if (task < NTASK) {
            int drx = task / 9;
            int c0  = (task % 9) * 8;
            int rr  = hr + drx - VRAD;
            bool rowok = (rr >= 0 && rr <= HH - PP);
            if (rowok) {
                float dot[8];
                float colsq[18];
#pragma unroll
                for (int c = 0; c < 8; c++) dot[c] = 0.f;
#pragma unroll
                for (int j2 = 0; j2 < 18; j2++) colsq[j2] = 0.f;
                for (int a = 0; a < PP; a++) {
                    const float* wrow = &win[drx + a][c0];
                    const float* rrow = &win[VRAD + a][VRAD];
                    float wv[18];
#pragma unroll
                    for (int j2 = 0; j2 < 18; j2++) wv[j2] = wrow[j2];
#pragma unroll
                    for (int j2 = 0; j2 < 18; j2++) colsq[j2] += wv[j2] * wv[j2];
#pragma unroll
                    for (int b = 0; b < PP; b++) {
                        float rv = rrow[b];
#pragma unroll
                        for (int c = 0; c < 8; c++)
                            dot[c] += wv[b + c] * rv;
                    }
                }
#pragma unroll
                for (int j2 = 1; j2 < 18; j2++) colsq[j2] += colsq[j2 - 1];
#pragma unroll
                for (int c = 0; c < 8; c++) {
                    int dcx = c0 + c;
                    int cc  = wr + dcx - VRAD;
                    float norm = colsq[c + 10] - (c ? colsq[c - 1] : 0.f);
                    if (dcx < WINW && cc >= 0 && cc <= WW - PP)
                        d[s][c] = norm - 2.f * dot[c];
                }
            }
            if (task == RTASK) d[s][0] = -INFD;
        }
    }

    float lval = INFD; int lidx = 0;
#pragma unroll
    for (int s = 0; s < 3; s++)
#pragma unroll
        for (int c = 0; c < 8; c++)
            if (d[s][c] < lval) { lval = d[s][c]; lidx = (s << 3) | c; }

    for (int sel = 0; sel < KSIM; sel++) {
        float rv = lval;
        int   ri = ((tid + ((lidx >> 3) << 8)) << 3) | (lidx & 7);
#pragma unroll
        for (int off = 32; off > 0; off >>= 1) {
            float ov = __shfl_down(rv, off);
            int   oi = __shfl_down(ri, off);
            if (ov < rv) { rv = ov; ri = oi; }
        }
        if ((tid & 63) == 0) { swv[tid >> 6] = rv; swi[tid >> 6] = ri; }
        __syncthreads();
        float bval = swv[0]; int bidx = swi[0];
#pragma unroll
        for (int w2 = 1; w2 < 4; w2++)
            if (swv[w2] < bval) { bval = swv[w2]; bidx = swi[w2]; }
        if (tid == 0) {
            int task = bidx >> 3;
            int drx = task / 9, dcx = (task % 9) * 8 + (bidx & 7);
            int prr = hr + drx - VRAD, pcc = wr + dcx - VRAD;
            inds[blk * KSIM + sel] = prr * NPOS + pcc;
        }
        __syncthreads();
        int otid = (bidx >> 3) & 255;
        if (tid == otid) {
            int code = (((bidx >> 3) >> 8) << 3) | (bidx & 7);
            lval = INFD; lidx = 0;
#pragma unroll
            for (int s = 0; s < 3; s++)
#pragma unroll
                for (int c = 0; c < 8; c++) {
                    if (((s << 3) | c) == code) d[s][c] = INFD;
                    if (d[s][c] < lval) { lval = d[s][c]; lidx = (s << 3) | c; }
                }
        }
    }
}

// ---------------------------------------------------------------------------
// Stage 2+3: tiled denoise. One block = 4x4 neighboring groups. Each wave
// owns 4 groups (16 lanes each); Q/Cholesky/solves/theta fully in registers
// with shfl(width=16) broadcasts — no block barriers in the math. All patch
// updates accumulate into an LDS 84x84 float2 tile (LDS atomics), flushed
// once to global with skip-if-empty: ~5x fewer device-scope atomics.
// ---------------------------------------------------------------------------
__global__ __launch_bounds__(256, 2)
void dn_kernel(const float* __restrict__ y, const int* __restrict__ inds,
               float2* __restrict__ nd, int R)
{
    __shared__ float2 acc[FOOT][FPITCH];   // 57.1 KB

    const int blk = blockIdx.x;
    const int n  = blk / (NTIL*NTIL);
    const int tr = blk % (NTIL*NTIL);
    const int ti = tr / NTIL, tj = tr % NTIL;
    const int tid = threadIdx.x;
    const int r0 = 3*(ti*TDIM) - VRAD;     // footprint origin (may be <0)
    const int c0 = 3*(tj*TDIM) - VRAD;
    const float* img = y + n * HH * WW;

    {   // zero the tile
        float* af = (float*)acc;
        for (int t = tid; t < FOOT*FPITCH*2; t += 256) af[t] = 0.f;
    }
    __syncthreads();

    const int wv2  = tid >> 6;         // wave id: ref-row within tile
    const int lane = tid & 63;
    const int sg   = lane >> 4;        // subgroup: ref-col within tile
    const int r    = lane & 15;        // k-index (matrix row / column owner)
    const int g    = n * (HREF*WREF) + (ti*TDIM + wv2) * WREF + (tj*TDIM + sg);

    const int idx  = inds[g * KSIM + r];
    const int prow = idx / NPOS, pcol = idx % NPOS;
    const float* pbase = img + prow * WW + pcol;

    // ---- Q = Y Y^T + E I, row r of Q in q[0..15] ----
    float q[16];
#pragma unroll
    for (int m = 0; m < 16; m++) q[m] = (m == r) ? EPS_E : 0.f;
    for (int a = 0; a < PP; a++) {
        float yr[PP];
#pragma unroll
        for (int b = 0; b < PP; b++) yr[b] = pbase[a * WW + b];
#pragma unroll
        for (int b = 0; b < PP; b++) {
            float yj = yr[b];
#pragma unroll
            for (int m = 0; m < 16; m++) {
                float ym = __shfl(yj, m, 16);
                q[m] += yj * ym;
            }
        }
    }

    // ---- in-register Cholesky: q becomes row r of L (cols <= r valid) ----
#pragma unroll
    for (int c = 0; c < 16; c++) {
        float dc = __shfl(q[c], c, 16);       // Q_schur[c][c] from lane c
        float s  = sqrtf(dc);
        float inv = 1.f / s;
        q[c] = (r == c) ? s : q[c] * inv;     // L[r][c] (r>c); garbage r<c unused
#pragma unroll
        for (int b = c + 1; b < 16; b++) {
            float lb = __shfl(q[c], b, 16);   // L[b][c]
            q[b] -= q[c] * lb;                // harmless on rows r<=c (unused)
        }
    }

    // ---- joint triangular solves: lane r computes column r of Qinv ----
    float z[16];
#pragma unroll
    for (int rr = 0; rr < 16; rr++) {
        float s = (rr == r) ? 1.f : 0.f;
        float diag = 0.f;
#pragma unroll
        for (int m = 0; m <= rr; m++) {
            float lrm = __shfl(q[m], rr, 16);  // L[rr][m]
            if (m < rr) s -= lrm * z[m];
            else diag = lrm;
        }
        z[rr] = s / diag;
    }
    float x[16];
#pragma unroll
    for (int rr = 15; rr >= 0; rr--) {
        float s = z[rr];
        float diag = 0.f;
#pragma unroll
        for (int m = 15; m >= rr; m--) {
            float lmr = __shfl(q[rr], m, 16);  // L[m][rr]
            if (m > rr) s -= lmr * x[m];
            else diag = lmr;
        }
        x[rr] = s / diag;                      // Qinv[:,r] == Qinv[r,:] (symm)
    }

    // ---- theta row r (theta symmetric), weight w ----
    float s1 = 0.f;
#pragma unroll
    for (int b = 0; b < 16; b++) s1 += x[b];
    float s2 = s1;
#pragma unroll
    for (int mask = 1; mask < 16; mask <<= 1) s2 += __shfl_xor(s2, mask, 16);
    float th[16], tsq = 0.f;
#pragma unroll
    for (int b = 0; b < 16; b++) {
        float s1b = __shfl(s1, b, 16);
        float t = ((b == r) ? 1.f : 0.f) - (x[b] - s1 * s1b / s2) * DE_C;
        th[b] = t;
        tsq += t * t;
    }
    tsq = fminf(fmaxf(tsq, 1.f / (float)KSIM), 1.f);
    const float w = 1.f / tsq;

    // ---- xhat[r] = sum_m theta[r][m] * Y[m]; accumulate into LDS tile ----
    const int arow = prow - r0, acol = pcol - c0;
    for (int a = 0; a < PP; a++) {
        float yr[PP];
#pragma unroll
        for (int b = 0; b < PP; b++) yr[b] = pbase[a * WW + b];
#pragma unroll
        for (int b = 0; b < PP; b++) {
            float yj = yr[b];
            float xh = 0.f;
#pragma unroll
            for (int m = 0; m < 16; m++) {
                float ym = __shfl(yj, m, 16);
                xh += th[m] * ym;
            }
            float2* cell = &acc[arow + a][acol + b];
            atomicAdd(&cell->x, w * xh);
            atomicAdd(&cell->y, w);
        }
    }
    __syncthreads();

    // ---- flush tile to global (skip empty cells) ----
    float2* ndI = nd + ((size_t)(blk & (R - 1)) * NIMG + n) * HH * WW;
    for (int t = tid; t < FOOT * FOOT; t += 256) {
        int rr = t / FOOT, cc = t % FOOT;
        float2 v = acc[rr][cc];
        if (v.y != 0.f) {
            int gr = r0 + rr, gc = c0 + cc;   // always in-image when v.y!=0
            int px = gr * WW + gc;
#if defined(__has_builtin) && __has_builtin(__builtin_amdgcn_global_atomic_fadd_v2f32)
            typedef float v2f __attribute__((ext_vector_type(2)));
            __builtin_amdgcn_global_atomic_fadd_v2f32((v2f*)&ndI[px], (v2f){v.x, v.y});
#else
            atomicAdd(&ndI[px].x, v.x);
            atomicAdd(&ndI[px].y, v.y);
#endif
        }
    }
}

// ---------------------------------------------------------------------------
// Stage 4: out = sum_r num_r / sum_r den_r
// ---------------------------------------------------------------------------
__global__ __launch_bounds__(256)
void fin_kernel(const float2* __restrict__ nd, float* __restrict__ out, int R)
{
    int t = blockIdx.x * 256 + threadIdx.x;
    if (t < NIMG * HH * WW) {
        float sn = 0.f, sd = 0.f;
        for (int r = 0; r < R; r++) {
            float2 v = nd[(size_t)r * NIMG * HH * WW + t];
            sn += v.x; sd += v.y;
        }
        out[t] = sn / sd;
    }
}

extern "C" void kernel_launch(void* const* d_in, const int* in_sizes, int n_in,
                              void* d_out, int out_size, void* d_ws, size_t ws_size,
                              hipStream_t stream)
{
    const float* y = (const float*)d_in[0];
    float* out = (float*)d_out;

    size_t indsBytes = (size_t)NGROUP * KSIM * sizeof(int);
    size_t perRep    = (size_t)NIMG * HH * WW * sizeof(float2);
    int R = 1;
    while (R < 4 && indsBytes + perRep * (size_t)(R * 2) <= ws_size) R <<= 1;

    float2* nd  = (float2*)d_ws;
    int*    inds = (int*)((char*)d_ws + perRep * (size_t)R);

    hipMemsetAsync(nd, 0, perRep * (size_t)R, stream);
    bm_kernel<<<NGROUP, 256, 0, stream>>>(y, inds);
    dn_kernel<<<NIMG * NTIL * NTIL, 256, 0, stream>>>(y, inds, nd, R);
    fin_kernel<<<(NIMG * HH * WW + 255) / 256, 256, 0, stream>>>(nd, out, R);
}